// Round 1
// 625.916 us; speedup vs baseline: 1.0660x; 1.0660x over previous
//
#include <hip/hip_runtime.h>
#include <stdint.h>

// Problem constants (SRUCell): L=1024, B=32, IN=1024, D=1024
#define L_   1024
#define B_   32
#define IN_  1024
#define D_   1024
#define M_   (L_ * B_)   // 32768  GEMM rows
#define N4_  (4 * D_)    // 4096   GEMM cols
#define K_   IN_         // 1024   GEMM inner

#define L2E      1.4426950408889634f
#define TWO_L2E  2.8853900817779268f

typedef _Float16 f16x8 __attribute__((ext_vector_type(8)));  // 8 fp16 = 4 VGPRs
typedef float    f32x4 __attribute__((ext_vector_type(4)));

#define GLB(p) (const __attribute__((address_space(1))) void*)(p)
#define LDSP(p) (__attribute__((address_space(3))) void*)(p)

__device__ __forceinline__ unsigned short f2h(float f) {
  _Float16 h = (_Float16)f;  // RNE
  return __builtin_bit_cast(unsigned short, h);
}
__device__ __forceinline__ float h2f(unsigned short b) {
  return (float)__builtin_bit_cast(_Float16, b);
}

// ---------------------------------------------------------------- cvt x -> fp16
__global__ void cvt_x(const float* __restrict__ x, unsigned short* __restrict__ xh) {
  int i = (blockIdx.x * 256 + threadIdx.x) * 4;
  float4 v = *(const float4*)(x + i);
  ushort4 o;
  o.x = f2h(v.x); o.y = f2h(v.y); o.z = f2h(v.z); o.w = f2h(v.w);
  *(ushort4*)(xh + i) = o;
}

// ------------------------------------------- transpose W (K_ x N4_) -> Wt fp16 (N4_ x K_)
// Gate columns n&3==1 (f) and n&3==2 (r) are pre-scaled by log2(e) so the scan's
// sigmoids run in exp2 domain with no extra multiply.
__global__ void cvt_wt(const float* __restrict__ W, unsigned short* __restrict__ Wt) {
  __shared__ float t[32][33];  // +1 pad breaks bank conflicts
  int tx = threadIdx.x, ty = threadIdx.y;
  int x0 = blockIdx.x * 32, y0 = blockIdx.y * 32;
  t[ty][tx] = W[(size_t)(y0 + ty) * N4_ + x0 + tx];
  __syncthreads();
  int n = x0 + ty;
  int g = n & 3;
  float s = (g == 1 || g == 2) ? L2E : 1.0f;
  Wt[(size_t)n * K_ + y0 + tx] = f2h(t[tx][ty] * s);
}

// ---------------------------------------------------------------- GEMM (256x256 8-phase)
// U[m][n] = sum_k A[m][k]*Bt[n][k]. 256x256 tile, BK=64, 8 waves (2Mx4N), 128 KiB LDS.
// LDS: per matrix 2 slots x 2 K-halves, each half [256 rows][32 k] f16 = 16 KB,
// subtiled 16x(16 rows x 32 k) with st_16x32 XOR swizzle (byte^=((byte>>9)&1)<<5).
// global_load_lds writes LDS linearly -> inverse swizzle applied to GLOBAL source
// (rule #21); ds_read applies the swizzle. Counted vmcnt(8) every 2nd phase; raw
// s_barrier (no vmcnt(0) drain in loop); setprio around MFMA clusters.
//
// Schedule (iter it computes tiles 2it [slot0] in ph1-4 and 2it+1 [slot1] in ph5-8;
// each phase stages one half for the tile 1-2 ahead, into a half whose last read
// was before the previous trailing barrier):
//   ph1: S0/kk0/Mlo  stage A(s1,kk1)<-t(2it+1)   ph5: S1/kk0/Mlo  stage A(s0,kk1)<-t(2it+2)
//   ph2: S0/kk0/Mhi  stage B(s1,kk1), vmcnt(8)   ph6: S1/kk0/Mhi  stage B(s0,kk1), vmcnt(8)
//   ph3: S0/kk1/Mlo  stage A(s0,kk0)<-t(2it+2)   ph7: S1/kk1/Mlo  stage A(s1,kk0)<-t(2it+3)
//   ph4: S0/kk1/Mhi  stage B(s0,kk0), vmcnt(8)   ph8: S1/kk1/Mhi  stage B(s1,kk0), vmcnt(8)
// Out-of-range tile indices clamp to 15 (L2-hot garbage, never computed) so the
// vmcnt counting stays uniform with no loop peel.

#define BARRIER() do { __builtin_amdgcn_sched_barrier(0); __builtin_amdgcn_s_barrier(); \
                       __builtin_amdgcn_sched_barrier(0); } while (0)
#define VMW8 asm volatile("s_waitcnt vmcnt(8)" ::: "memory")
#define SBAR0 __builtin_amdgcn_sched_barrier(0)

__device__ __forceinline__ void stage_half(const unsigned short* __restrict__ g,
                                           unsigned short* __restrict__ half_,
                                           int rowbase, int ktile, int kk,
                                           int wave, int srow, int skel) {
  const int kt = ktile < 15 ? ktile : 15;  // clamp: keeps loads in-bounds & uniform
  const unsigned short* g0 =
      g + (size_t)(rowbase + wave * 32 + srow) * K_ + kt * 64 + kk * 32 + skel;
  // chunk = wave*2 (+1): 1024 B per issue, lane i -> base + i*16 (HW linear)
  __builtin_amdgcn_global_load_lds(GLB(g0), LDSP(half_ + wave * 1024), 16, 0, 0);
  __builtin_amdgcn_global_load_lds(GLB(g0 + (size_t)16 * K_),
                                   LDSP(half_ + wave * 1024 + 512), 16, 0, 0);
}

__global__ __launch_bounds__(512, 2) void gemm_u(const unsigned short* __restrict__ A,
                                                 const unsigned short* __restrict__ Bt,
                                                 unsigned short* __restrict__ U) {
  __shared__ unsigned short lds[65536];  // 128 KiB: A halves [0,32768), B halves [32768,65536)

  const int tid  = threadIdx.x;
  const int wave = tid >> 6;   // 0..7
  const int lane = tid & 63;
  const int l15  = lane & 15;
  const int quad = lane >> 4;
  const int wm   = wave >> 2;  // 0..1 (M), 128 rows each
  const int wn   = wave & 3;   // 0..3 (N), 64 cols each

  // XCD-aware bijective swizzle: 2048 blocks, 8 XCDs, 256 per XCD (2048%8==0)
  const int bid = blockIdx.x;
  const int swz = (bid & 7) * 256 + (bid >> 3);
  const int n0  = (swz & 15) * 256;
  const int m0  = (swz >> 4) * 256;

  // staging inverse-swizzle decode (per lane): row & k-element within a 16x32 chunk
  const int srow = lane >> 2;
  const int skel = ((lane & 3) * 8) ^ ((lane >= 32) ? 16 : 0);

  // ds_read swizzled offset within a half (elements): row l15, k quad*8, XOR 16 elems if row>=8
  const int roff = (l15 * 32 + quad * 8) ^ ((l15 >= 8) ? 16 : 0);

#define HA(s, h) (lds + ((s)*2 + (h)) * 8192)
#define HB(s, h) (lds + 32768 + ((s)*2 + (h)) * 8192)

  f32x4 acc[8][4];
#pragma unroll
  for (int i = 0; i < 8; i++)
#pragma unroll
    for (int j = 0; j < 4; j++) acc[i][j] = (f32x4){0.f, 0.f, 0.f, 0.f};

  // prologue: t0.kk0(A,B), t0.kk1(A,B), t1.kk0(A,B) = 12 loads; retire first 4 (t0.kk0)
  stage_half(A,  HA(0, 0), m0, 0, 0, wave, srow, skel); SBAR0;
  stage_half(Bt, HB(0, 0), n0, 0, 0, wave, srow, skel); SBAR0;
  stage_half(A,  HA(0, 1), m0, 0, 1, wave, srow, skel); SBAR0;
  stage_half(Bt, HB(0, 1), n0, 0, 1, wave, srow, skel); SBAR0;
  stage_half(A,  HA(1, 0), m0, 1, 0, wave, srow, skel); SBAR0;
  stage_half(Bt, HB(1, 0), n0, 1, 0, wave, srow, skel); SBAR0;
  VMW8;
  BARRIER();

  f16x8 afr[4], bfr[4];

#define PHASE(S, KK, MH, GMAT, LHALF, ROWB, KT, KH, DO_VMW)                        \
  {                                                                                \
    const unsigned short* ha = HA(S, KK);                                          \
    if ((MH) == 0) {                                                               \
      const unsigned short* hb = HB(S, KK);                                        \
      _Pragma("unroll") for (int ni = 0; ni < 4; ++ni)                             \
          bfr[ni] = *(const f16x8*)(hb + (wn * 4 + ni) * 512 + roff);              \
    }                                                                              \
    _Pragma("unroll") for (int mi = 0; mi < 4; ++mi)                               \
        afr[mi] = *(const f16x8*)(ha + (wm * 8 + (MH)*4 + mi) * 512 + roff);       \
    stage_half(GMAT, LHALF, ROWB, KT, KH, wave, srow, skel);                       \
    BARRIER();                                                                     \
    __builtin_amdgcn_s_setprio(1);                                                 \
    _Pragma("unroll") for (int mi = 0; mi < 4; ++mi)                               \
        _Pragma("unroll") for (int ni = 0; ni < 4; ++ni)                           \
            acc[(MH)*4 + mi][ni] = __builtin_amdgcn_mfma_f32_16x16x32_f16(         \
                afr[mi], bfr[ni], acc[(MH)*4 + mi][ni], 0, 0, 0);                  \
    __builtin_amdgcn_s_setprio(0);                                                 \
    if (DO_VMW) VMW8;                                                              \
    BARRIER();                                                                     \
  }

#pragma unroll 1
  for (int it = 0; it < 8; ++it) {
    const int t1 = 2 * it + 1, t2 = 2 * it + 2, t3 = 2 * it + 3;
    PHASE(0, 0, 0, A,  HA(1, 1), m0, t1, 1, 0)
    PHASE(0, 0, 1, Bt, HB(1, 1), n0, t1, 1, 1)
    PHASE(0, 1, 0, A,  HA(0, 0), m0, t2, 0, 0)
    PHASE(0, 1, 1, Bt, HB(0, 0), n0, t2, 0, 1)
    PHASE(1, 0, 0, A,  HA(0, 1), m0, t2, 1, 0)
    PHASE(1, 0, 1, Bt, HB(0, 1), n0, t2, 1, 1)
    PHASE(1, 1, 0, A,  HA(1, 0), m0, t3, 0, 0)
    PHASE(1, 1, 1, Bt, HB(1, 0), n0, t3, 0, 1)
  }
#undef PHASE

  // epilogue: C/D layout col = lane&15 (N), row = quad*4 + reg (M); store fp16
#pragma unroll
  for (int mi = 0; mi < 8; ++mi) {
#pragma unroll
    for (int ni = 0; ni < 4; ++ni) {
      const int row = m0 + wm * 128 + mi * 16 + quad * 4;
      const int col = n0 + wn * 64 + ni * 16 + l15;
#pragma unroll
      for (int i = 0; i < 4; ++i)
        U[(size_t)(row + i) * N4_ + col] = f2h(acc[mi][ni][i]);
    }
  }
#undef HA
#undef HB
}

// ---------------------------------------------------------------- sequential scan
// One thread per (b,d) chain; t = b*D_+d. U uint2 index for step l is l*32768 + t.
// Gates arrive pre-scaled by log2(e) (u1', u2'), so sigmoid = rcp(1+exp2(-p)).
// PF=16 prefetch: 16 steps x ~70 cyc covers ~1100 cyc >> 900 cyc HBM latency.
__global__ __launch_bounds__(64) void scan_kernel(const unsigned short* __restrict__ U,
                                                  const float* __restrict__ c0,
                                                  const float* __restrict__ V,
                                                  const float* __restrict__ bias,
                                                  float* __restrict__ out) {
  const int t = blockIdx.x * 64 + threadIdx.x;  // 0..32767
  const int d = t & (D_ - 1);
  float c = c0[t];
  const float vfp = V[d] * L2E, vrp = V[D_ + d] * L2E;
  const float bfp = bias[d] * L2E, brp = bias[D_ + d] * L2E;
  const uint2* Up = (const uint2*)U;  // 4 fp16 gates per uint2

  constexpr int PF = 16;
  uint2 buf[PF];
#pragma unroll
  for (int j = 0; j < PF; j++) buf[j] = Up[(size_t)j * 32768 + t];

#define SRU_STEP(u, l)                                                          \
  {                                                                             \
    const float u0 = h2f((unsigned short)((u).x & 0xffffu));                    \
    const float u1 = h2f((unsigned short)((u).x >> 16)); /* pre-scaled */       \
    const float u2 = h2f((unsigned short)((u).y & 0xffffu)); /* pre-scaled */   \
    const float u3 = h2f((unsigned short)((u).y >> 16));                        \
    const float pf = fmaf(c, vfp, u1 + bfp);                                    \
    const float pr = fmaf(c, vrp, u2 + brp);                                    \
    const float f  = __builtin_amdgcn_rcpf(1.f + __builtin_amdgcn_exp2f(-pf));  \
    const float r  = __builtin_amdgcn_rcpf(1.f + __builtin_amdgcn_exp2f(-pr));  \
    c = fmaf(c - u0, f, u0);                                                    \
    const float q  = __builtin_amdgcn_exp2f(c * TWO_L2E);                       \
    const float th = fmaf(-2.f, __builtin_amdgcn_rcpf(1.f + q), 1.f);           \
    const float h  = fmaf(th - u3, r, u3);                                      \
    __builtin_nontemporal_store(h, out + (size_t)(l) * 32768 + t);              \
  }

#pragma unroll 1
  for (int l0 = 0; l0 < L_ - PF; l0 += PF) {
#pragma unroll
    for (int j = 0; j < PF; j++) {
      uint2 u = buf[j];
      buf[j] = Up[(size_t)(l0 + j + PF) * 32768 + t];  // unconditional prefetch
      SRU_STEP(u, l0 + j);
    }
  }
  // tail: last PF steps, no prefetch
#pragma unroll
  for (int j = 0; j < PF; j++) {
    uint2 u = buf[j];
    SRU_STEP(u, L_ - PF + j);
  }
#undef SRU_STEP

  out[(size_t)L_ * 32768 + t] = c;  // c_last appended after h
}

extern "C" void kernel_launch(void* const* d_in, const int* in_sizes, int n_in,
                              void* d_out, int out_size, void* d_ws, size_t ws_size,
                              hipStream_t stream) {
  const float* x    = (const float*)d_in[0];
  const float* c0   = (const float*)d_in[1];
  const float* W    = (const float*)d_in[2];
  const float* V    = (const float*)d_in[3];
  const float* bias = (const float*)d_in[4];
  float* out = (float*)d_out;

  uint8_t* ws = (uint8_t*)d_ws;
  unsigned short* Xh = (unsigned short*)ws;                          // 64 MB fp16 x
  unsigned short* Wt = (unsigned short*)(ws + ((size_t)64 << 20));   // 8 MB fp16 W^T
  unsigned short* U  = (unsigned short*)(ws + ((size_t)72 << 20));   // 256 MB fp16 U
  // total workspace: 328 MB

  cvt_x<<<(M_ * K_) / 1024, 256, 0, stream>>>(x, Xh);
  cvt_wt<<<dim3(N4_ / 32, K_ / 32), dim3(32, 32), 0, stream>>>(W, Wt);
  gemm_u<<<2048, 512, 0, stream>>>(Xh, Wt, U);
  scan_kernel<<<(B_ * D_) / 64, 64, 0, stream>>>(U, c0, V, bias, out);
}